// Round 5
// baseline (447.080 us; speedup 1.0000x reference)
//
#include <hip/hip_runtime.h>
#include <hip/hip_fp16.h>

#define XDIM 256
#define YDIM 256
#define ZDIM 32
#define NT 384
#define NA 180
#define AG 4                    // angles per block
#define SW 263                  // dwords per staged row (odd -> bank spread)
#define SROWS 70                // 3 pad + 64 data + 3 pad
#define SLICE_DW (SROWS * SW)   // 18410 dwords = 73640 B
#define SMEM_BYTES 73664        // rounded; psum (8 KB) aliases the slice

// Block: one z-PAIR x 4 angles x one y-HALF (2 strips of 64 rows), 1024 thr.
// 73.6 KB LDS -> 2 blocks/CU = 32 waves/CU *if* VGPR <= 64. Round 3 proved
// forcing that via __launch_bounds__(1024,8) makes the allocator spill
// (VGPR 32, 165 MB/dispatch scratch traffic, slower). So: plain launch
// bounds + slimmed persistent state (only c_,s_,acc survive the strip loop;
// bx/by/interval/partition recomputed per strip-angle — 8x ~20 ops, free).
// Halves combine with atomicAdd into a memset-zeroed output.
// LDS cell (y,x) holds half2(vol[z0],vol[z1]); packed-f16 x-lerp, f32 y-lerp.
// Pad 3 + ceil'd interval starts keeps every executed tap inside the stage;
// strip-boundary t's use identical fp expressions in both half-blocks ->
// exact partition (no gap / double count).
__global__ __launch_bounds__(1024) void proj_kernel(
    const float* __restrict__ vol, const float* __restrict__ phis,
    float* __restrict__ out) {
  extern __shared__ char smem[];
  __half2* sl = reinterpret_cast<__half2*>(smem);
  float2* psum = reinterpret_cast<float2*>(smem);  // reused after compute

  const int tid = threadIdx.x;
  const int zp = blockIdx.x;  // 0..15 z-pair
  const int ag = blockIdx.y;  // 0..44 angle group
  const int h = blockIdx.z;   // 0..1 y-half (strips 2h, 2h+1)
  const int col = tid & 255;
  const int q = tid >> 8;     // t-quarter (it % 4 == q)
  const float u = (float)col - 127.5f;

  float c_[AG], s_[AG];
#pragma unroll
  for (int j = 0; j < AG; ++j) {
    const float phi = phis[ag * AG + j] * 0.017453292519943295f;
    c_[j] = cosf(phi);
    s_[j] = sinf(phi);
  }

  float2 acc[AG];
#pragma unroll
  for (int j = 0; j < AG; ++j) acc[j] = make_float2(0.f, 0.f);

  const float* vsrc0 = vol + (zp * 2) * (YDIM * XDIM);
  const float* vsrc1 = vsrc0 + YDIM * XDIM;

#pragma unroll
  for (int st2 = 0; st2 < 2; ++st2) {
    const int st = h * 2 + st2;
    const int gr0 = st * 64 - 3;  // global row of local row 0
    __syncthreads();              // prior strip's reads done before overwrite

    // ---- col pads: lx in {0,1,2} u {259..262}, all 70 rows (7*70=490 thr)
    if (tid < SROWS * 7) {
      int r = tid / 7;
      int cc = tid - r * 7;
      int lx = cc < 3 ? cc : cc + 256;
      sl[r * SW + lx] = __floats2half2_rn(0.f, 0.f);
    }
    // ---- fill 70 rows x 256 cols; out-of-volume rows write zeros (row pads)
    for (int i = 0; i < 18; ++i) {
      int k = tid + (i << 10);
      if (k < SROWS * 256) {
        int r = k >> 8;
        int x = k & 255;
        int gr = gr0 + r;
        __half2 v = __floats2half2_rn(0.f, 0.f);
        if ((unsigned)gr < 256u) {
          int gi = gr * XDIM + x;
          v = __floats2half2_rn(vsrc0[gi], vsrc1[gi]);
        }
        sl[r * SW + x + 3] = v;
      }
    }
    __syncthreads();

    // cell index: lr = y0 - gr0 = y0 + 3 - 64*st, lx = x0 + 3
    const int K = (3 - 64 * st) * SW + 3;
#pragma unroll
    for (int j = 0; j < AG; ++j) {
      const float c = c_[j], s = s_[j];
      const float bx = fmaf(u, -s, 127.5f);
      const float by = fmaf(u, c, 127.5f);

      // global t-interval (widened +-2; ceil keeps excursion <= 2|slope| < 3)
      float flo = 0.f, fhi = (float)NT;
      if (fabsf(c) < 1e-6f) {
        if (bx <= -1.f || bx >= 256.f) { flo = 1.f; fhi = 0.f; }
      } else {
        float t1 = (-1.f - bx) / c + 191.5f;
        float t2 = (256.f - bx) / c + 191.5f;
        flo = fmaxf(flo, fminf(t1, t2) - 2.f);
        fhi = fminf(fhi, fmaxf(t1, t2) + 2.f);
      }
      if (fabsf(s) < 1e-6f) {
        if (by <= -1.f || by >= 256.f) { flo = 1.f; fhi = 0.f; }
      } else {
        float t1 = (-1.f - by) / s + 191.5f;
        float t2 = (256.f - by) / s + 191.5f;
        flo = fmaxf(flo, fminf(t1, t2) - 2.f);
        fhi = fminf(fhi, fmaxf(t1, t2) + 2.f);
      }
      const int glo = (int)ceilf(fmaxf(flo, 0.f));
      const int ghi = (int)fminf(fhi, (float)NT);

      // strip ownership: identical fp expressions in both half-blocks
      int lo, hi;
      if (fabsf(s) < 1e-6f) {
        int stown = min(3, max(0, ((int)floorf(by)) >> 6));
        lo = (st == stown) ? glo : 0;
        hi = (st == stown) ? ghi : 0;
      } else {
        float ta = ((float)(64 * st) - by) / s + 191.5f;
        float tb = ((float)(64 * st + 64) - by) / s + 191.5f;
        int ia = (int)ceilf(ta);
        int ib = (int)ceilf(tb);
        if (s > 0.f) {
          lo = (st == 0) ? glo : max(glo, ia);
          hi = (st == 3) ? ghi : min(ghi, ib);
        } else {
          lo = (st == 3) ? glo : max(glo, ib);
          hi = (st == 0) ? ghi : min(ghi, ia);
        }
      }
      const int start = lo + ((q - lo) & 3);
      float t = (float)start - 191.5f;  // half-integers: t += 4 exact in fp32
      const float tend = (float)hi - 191.5f;
      float a0 = acc[j].x, a1 = acc[j].y;
#pragma unroll 2
      for (; t < tend; t += 4.f) {
        float x = fmaf(t, c, bx);
        float y = fmaf(t, s, by);
        float x0f = floorf(x), y0f = floorf(y);
        float fx = x - x0f, fy = y - y0f;
        int ai = (int)fmaf(y0f, (float)SW, x0f) + K;  // exact: |.| < 2^24
        const __half2* p = sl + ai;
        __half2 d00 = p[0], d01 = p[1], d10 = p[SW], d11 = p[SW + 1];
        __half2 fx2 = __float2half2_rn(fx);
        __half2 hx0 = __hfma2(__hsub2(d01, d00), fx2, d00);  // x-lerp, both z
        __half2 hx1 = __hfma2(__hsub2(d11, d10), fx2, d10);
        float omfy = 1.f - fy;
        a0 = fmaf(__low2float(hx0), omfy, a0);
        a0 = fmaf(__low2float(hx1), fy, a0);
        a1 = fmaf(__high2float(hx0), omfy, a1);
        a1 = fmaf(__high2float(hx1), fy, a1);
      }
      acc[j].x = a0; acc[j].y = a1;
    }
  }

  // ---- reduce 4 t-quarters (psum aliases slice LDS) and combine y-halves
#pragma unroll
  for (int j = 0; j < AG; ++j) {
    __syncthreads();
    psum[tid] = acc[j];
    __syncthreads();
    if (tid < 256) {
      float2 pa = psum[col], pb = psum[256 + col], pc = psum[512 + col],
             pd = psum[768 + col];
      const int a = ag * AG + j;
      atomicAdd(&out[(a * ZDIM + zp * 2) * XDIM + col],
                pa.x + pb.x + pc.x + pd.x);
      atomicAdd(&out[(a * ZDIM + zp * 2 + 1) * XDIM + col],
                pa.y + pb.y + pc.y + pd.y);
    }
  }
}

extern "C" void kernel_launch(void* const* d_in, const int* in_sizes, int n_in,
                              void* d_out, int out_size, void* d_ws, size_t ws_size,
                              hipStream_t stream) {
  const float* vol = (const float*)d_in[0];
  const float* phis = (const float*)d_in[1];
  float* out = (float*)d_out;
  (void)hipFuncSetAttribute((const void*)proj_kernel,
                            hipFuncAttributeMaxDynamicSharedMemorySize,
                            SMEM_BYTES);
  // halves accumulate via atomics -> output must start zeroed
  (void)hipMemsetAsync(out, 0, out_size, stream);
  dim3 grid(ZDIM / 2, NA / AG, 2);
  proj_kernel<<<grid, 1024, SMEM_BYTES, stream>>>(vol, phis, out);
}

// Round 8
// 396.550 us; speedup vs baseline: 1.1274x; 1.1274x over previous
//
#include <hip/hip_runtime.h>
#include <hip/hip_fp16.h>

#define XDIM 256
#define YDIM 256
#define ZDIM 32
#define NT 384
#define NA 180
#define AG 4                     // angles per block
#define SW 263                   // dwords per staged row (263%32=7 -> bank spread)
#define SROWS 134                // 3 pad + 128 data + 3 pad
#define SLICE_DW (SROWS * SW)    // 35242 dwords = 140968 B
#define SMEM_BYTES 140976        // 1 block/CU; psum (8 KB) aliases the slice

// Block = one z-PAIR x 4 angles, looping over 2 row-strips of 128.
// Round 3/5 lesson: occupancy-chasing (forced launch bounds -> spill; y-half
// block split -> wave idleness + no residency gain) loses to the 1-block/CU
// shape. This round keeps that shape and attacks the measured regime
// (per-SIMD issue ~17%, LDS ~40%: latency-bound + strip imbalance):
//  1) AXIS CHOICE: stage transposed when |s|<|c| so the strip axis is always
//     the fast-crossing ray coordinate (|row slope| >= 0.65 for all angles).
//     Every ray crosses both strips -> all 16 waves active in every strip
//     phase (was: half idle for near-horizontal angles).
//  2) ILP: counted loop + unroll 4 -> 4 samples / 8 ds_read2 in flight per
//     wave; launch_bounds(1024,2) lifts the VGPR cap to 256 (no spill risk).
//  3) No atomics/memset (block owns full rays); psum as two stride-1 float
//     arrays (kills the float2 4-way write conflict).
// LDS cell (r,w) holds half2(vol[z0],vol[z1]); packed-f16 col-lerp, f32
// row-lerp. Pad 3 + ceil'd starts keep every executed tap staged; strip
// boundary t's are identical fp expressions in both strips -> exact split.
__global__ __launch_bounds__(1024, 2) void proj_kernel(
    const float* __restrict__ vol, const float* __restrict__ phis,
    float* __restrict__ out) {
  extern __shared__ char smem[];
  __half2* sl = reinterpret_cast<__half2*>(smem);
  float* ps = reinterpret_cast<float*>(smem);  // 2048 floats, aliases slice

  const int tid = threadIdx.x;
  const int zp = blockIdx.x;  // 0..15 z-pair
  const int ag = blockIdx.y;  // 0..44 angle group
  const int col = tid & 255;
  const int q = tid >> 8;     // t-quarter (it % 4 == q)
  const float u = (float)col - 127.5f;

  // block-uniform axis choice from the group's first angle:
  // ax=1 -> strips along y (row=y,col=x); ax=0 -> transposed (row=x,col=y)
  const float phi0 = phis[ag * AG] * 0.017453292519943295f;
  const int ax = (fabsf(sinf(phi0)) >= fabsf(cosf(phi0))) ? 1 : 0;

  float c_[AG], s_[AG];
#pragma unroll
  for (int j = 0; j < AG; ++j) {
    const float phi = phis[ag * AG + j] * 0.017453292519943295f;
    c_[j] = cosf(phi);
    s_[j] = sinf(phi);
  }
  float2 acc[AG];
#pragma unroll
  for (int j = 0; j < AG; ++j) acc[j] = make_float2(0.f, 0.f);

  const float* vsrc0 = vol + (zp * 2) * (YDIM * XDIM);
  const float* vsrc1 = vsrc0 + YDIM * XDIM;

#pragma unroll
  for (int st = 0; st < 2; ++st) {
    const int gr0 = st * 128 - 3;  // global row index of local row 0
    __syncthreads();               // prior strip reads / psum done

    // col pads: lw in {0,1,2} u {259..262}, all rows (7*134=938 threads)
    if (tid < SROWS * 7) {
      int r = tid / 7;
      int cc7 = tid - r * 7;
      int lw = cc7 < 3 ? cc7 : cc7 + 256;
      sl[r * SW + lw] = __floats2half2_rn(0.f, 0.f);
    }
    // fill 134 rows x 256 cols; out-of-range rows write zeros (row pads).
    // ax=1: cell(r,w)=vol[gr0+r][w] (coalesced). ax=0: cell(r,w)=vol[w][gr0+r]
    // (global stride-256 but L1-resident across passes; LDS writes stride-1).
    for (int i = 0; i < 34; ++i) {
      int k = tid + (i << 10);
      if (k < SROWS * 256) {
        int r = k >> 8;
        int w = k & 255;
        int gr = gr0 + r;
        __half2 v = __floats2half2_rn(0.f, 0.f);
        if ((unsigned)gr < 256u) {
          int gi = ax ? (gr * XDIM + w) : (w * XDIM + gr);
          v = __floats2half2_rn(vsrc0[gi], vsrc1[gi]);
        }
        sl[r * SW + w + 3] = v;
      }
    }
    __syncthreads();

    const int K = (3 - 128 * st) * SW + 3;  // ai = r0*SW + w0 + K
#pragma unroll
    for (int j = 0; j < AG; ++j) {
      const float c = c_[j], s = s_[j];
      const float bx = fmaf(u, -s, 127.5f);
      const float by = fmaf(u, c, 127.5f);
      const float cr = ax ? s : c, br = ax ? by : bx;  // row coord, |cr|>=.65
      const float cc = ax ? c : s, bc = ax ? bx : by;  // col coord

      // global t-interval (widen +-2; ceil start keeps taps in the 3-pad)
      float t1 = (-1.f - br) / cr + 191.5f;
      float t2 = (256.f - br) / cr + 191.5f;
      float flo = fmaxf(0.f, fminf(t1, t2) - 2.f);
      float fhi = fminf((float)NT, fmaxf(t1, t2) + 2.f);
      if (fabsf(cc) < 1e-6f) {
        if (bc <= -1.f || bc >= 256.f) { flo = 1.f; fhi = 0.f; }
      } else {
        float t3 = (-1.f - bc) / cc + 191.5f;
        float t4 = (256.f - bc) / cc + 191.5f;
        flo = fmaxf(flo, fminf(t3, t4) - 2.f);
        fhi = fminf(fhi, fmaxf(t3, t4) + 2.f);
      }
      const int glo = (int)ceilf(flo);
      const int ghi = (int)fhi;

      // strip partition on the row coord (never degenerate: |cr| >= 0.65);
      // identical boundary expressions across strips -> exact split
      float tba = ((float)(128 * st) - br) / cr + 191.5f;
      float tbb = ((float)(128 * st + 128) - br) / cr + 191.5f;
      int ia = (int)ceilf(tba);
      int ib = (int)ceilf(tbb);
      int lo, hi;
      if (cr > 0.f) {
        lo = (st == 0) ? glo : max(glo, ia);
        hi = (st == 1) ? ghi : min(ghi, ib);
      } else {
        lo = (st == 1) ? glo : max(glo, ib);
        hi = (st == 0) ? ghi : min(ghi, ia);
      }
      const int start = lo + ((q - lo) & 3);
      const int d = hi - start;
      int n = d > 0 ? (d + 3) >> 2 : 0;
      float t = (float)start - 191.5f;  // half-integers: t += 4 exact in fp32
      float a0 = acc[j].x, a1 = acc[j].y;
#pragma unroll 4
      for (int k = 0; k < n; ++k, t += 4.f) {
        float rr = fmaf(t, cr, br);
        float ww = fmaf(t, cc, bc);
        float r0f = floorf(rr), w0f = floorf(ww);
        float fr = rr - r0f, fw = ww - w0f;
        int ai = (int)fmaf(r0f, (float)SW, w0f) + K;  // exact: |.| < 2^24
        const __half2* p = sl + ai;
        __half2 d00 = p[0], d01 = p[1], d10 = p[SW], d11 = p[SW + 1];
        __half2 fw2 = __float2half2_rn(fw);
        __half2 h0 = __hfma2(__hsub2(d01, d00), fw2, d00);  // col-lerp, both z
        __half2 h1 = __hfma2(__hsub2(d11, d10), fw2, d10);
        float omfr = 1.f - fr;
        a0 = fmaf(__low2float(h0), omfr, a0);
        a0 = fmaf(__low2float(h1), fr, a0);
        a1 = fmaf(__high2float(h0), omfr, a1);
        a1 = fmaf(__high2float(h1), fr, a1);
      }
      acc[j].x = a0; acc[j].y = a1;
    }
  }

  // reduce 4 t-quarters (ps aliases dead slice; stride-1, conflict-free)
#pragma unroll
  for (int j = 0; j < AG; ++j) {
    __syncthreads();
    ps[tid] = acc[j].x;
    ps[1024 + tid] = acc[j].y;
    __syncthreads();
    if (tid < 256) {
      float r0 = ps[col] + ps[256 + col] + ps[512 + col] + ps[768 + col];
      float r1 = ps[1024 + col] + ps[1280 + col] + ps[1536 + col] +
                 ps[1792 + col];
      const int a = ag * AG + j;
      out[(a * ZDIM + zp * 2) * XDIM + col] = r0;
      out[(a * ZDIM + zp * 2 + 1) * XDIM + col] = r1;
    }
  }
}

extern "C" void kernel_launch(void* const* d_in, const int* in_sizes, int n_in,
                              void* d_out, int out_size, void* d_ws, size_t ws_size,
                              hipStream_t stream) {
  const float* vol = (const float*)d_in[0];
  const float* phis = (const float*)d_in[1];
  float* out = (float*)d_out;
  (void)hipFuncSetAttribute((const void*)proj_kernel,
                            hipFuncAttributeMaxDynamicSharedMemorySize,
                            SMEM_BYTES);
  dim3 grid(ZDIM / 2, NA / AG);
  proj_kernel<<<grid, 1024, SMEM_BYTES, stream>>>(vol, phis, out);
}

// Round 12
// 237.934 us; speedup vs baseline: 1.8790x; 1.6666x over previous
//
#include <hip/hip_runtime.h>
#include <hip/hip_fp16.h>

#define XDIM 256
#define YDIM 256
#define ZDIM 32
#define NT 384
#define NA 180
#define AG 2                      // angles per block
#define SW 263                    // 8B cells per staged row
#define SR 70                     // 3 pad + 64 data + 3 pad (strip axis)
#define CELLS (SR * SW)           // 18410 cells * 8B
#define SMEM_BYTES 147280         // 1 block/CU; float4 psum (16KB) aliases

// Block = one z-QUAD x 2 angles, looping over 4 strips of 64 rows along the
// FAST-crossing axis (ax=1: strip=y when |s|>=|c|, else strip=x). LDS cell
// (r,w) = uint2 of 4 fp16 (z0..z3): one geometry computation + 2 mergeable
// 16B LDS reads feed FOUR z-outputs (round-1 paid full geometry + 4 reads
// per TWO z). Round-8 lesson: ax=0 must stage with COALESCED global reads
// (64 consecutive floats per wave) + transposed LDS writes (stride-SW, bank
// spread 526%32=14 -> cheap), not strided global reads (64 lines/wave, the
// +68us regression). Axis choice guarantees |row slope|>=0.65 so every ray
// crosses all 4 strips -> no idle waves at strip barriers. Pad 3 + ceil'd
// interval starts keep every executed tap staged (same scheme that passed
// rounds 5/8); strip boundaries use identical fp expressions in all strips
// -> exact partition. No atomics/memset: block owns full rays.
__global__ __launch_bounds__(1024) void proj_kernel(
    const float* __restrict__ vol, const float* __restrict__ phis,
    float* __restrict__ out) {
  extern __shared__ char smem[];
  uint2* sl = reinterpret_cast<uint2*>(smem);
  float4* ps = reinterpret_cast<float4*>(smem);  // aliases slice when dead

  const int tid = threadIdx.x;
  const int zq = blockIdx.x;  // 0..7 z-quad
  const int ag = blockIdx.y;  // 0..89 angle group
  const int col = tid & 255;
  const int q = tid >> 8;     // t-quarter (it % 4 == q)
  const float u = (float)col - 127.5f;

  // block-uniform axis from the group's first angle:
  // ax=1 -> strip axis y (row=y,col=x); ax=0 -> strip axis x (row=x,col=y)
  const float phi0 = phis[ag * AG] * 0.017453292519943295f;
  const int ax = (fabsf(sinf(phi0)) >= fabsf(cosf(phi0))) ? 1 : 0;

  float c_[AG], s_[AG];
#pragma unroll
  for (int j = 0; j < AG; ++j) {
    const float phi = phis[ag * AG + j] * 0.017453292519943295f;
    c_[j] = cosf(phi);
    s_[j] = sinf(phi);
  }
  float4 acc[AG];
#pragma unroll
  for (int j = 0; j < AG; ++j) acc[j] = make_float4(0.f, 0.f, 0.f, 0.f);

  const float* vb = vol + (zq * 4) * (YDIM * XDIM);  // 4 slices, stride 64K

#pragma unroll
  for (int st = 0; st < 4; ++st) {
    const int gr0 = st * 64 - 3;  // global strip-axis index of local row 0
    __syncthreads();              // prior strip reads / psum done

    // col pads: lw in {0,1,2} u {259..262}, all 70 rows (7*70=490 threads)
    if (tid < SR * 7) {
      int r = tid / 7;
      int c7 = tid - r * 7;
      int lw = c7 < 3 ? c7 : c7 + 256;
      sl[r * SW + lw] = make_uint2(0u, 0u);
    }
    if (ax) {
      // cell(r,w)=vol[z][gr0+r][w]; thread k: r=k>>8, x=k&255 (coalesced)
      for (int i = 0; i < 18; ++i) {
        int k = tid + (i << 10);
        if (k < SR * 256) {
          int r = k >> 8, x = k & 255, gr = gr0 + r;
          uint2 v = make_uint2(0u, 0u);
          if ((unsigned)gr < 256u) {
            int gi = gr * XDIM + x;
            __half2 p = __floats2half2_rn(vb[gi], vb[gi + 65536]);
            __half2 qq = __floats2half2_rn(vb[gi + 131072], vb[gi + 196608]);
            v.x = *reinterpret_cast<unsigned*>(&p);
            v.y = *reinterpret_cast<unsigned*>(&qq);
          }
          sl[r * SW + x + 3] = v;
        }
      }
    } else {
      // cell(r,w)=vol[z][y=w][x=gr0+r]; global reads coalesced along x
      // pass A: r=0..63 -> wave reads vol[y][gr0..gr0+63] (256B contiguous)
      for (int i = 0; i < 16; ++i) {
        int k = tid + (i << 10);
        int r = k & 63, y = k >> 6, gx = gr0 + r;
        uint2 v = make_uint2(0u, 0u);
        if ((unsigned)gx < 256u) {
          int gi = y * XDIM + gx;
          __half2 p = __floats2half2_rn(vb[gi], vb[gi + 65536]);
          __half2 qq = __floats2half2_rn(vb[gi + 131072], vb[gi + 196608]);
          v.x = *reinterpret_cast<unsigned*>(&p);
          v.y = *reinterpret_cast<unsigned*>(&qq);
        }
        sl[r * SW + y + 3] = v;
      }
      // pass B: r=64..69 (6 rows x 256 y), width-8 tiles, 2 lanes/8 masked
      for (int i = 0; i < 2; ++i) {
        int k = tid + (i << 10);
        int rb = k & 7, y = k >> 3;
        if (rb < 6) {
          int r = 64 + rb, gx = gr0 + r;
          uint2 v = make_uint2(0u, 0u);
          if ((unsigned)gx < 256u) {
            int gi = y * XDIM + gx;
            __half2 p = __floats2half2_rn(vb[gi], vb[gi + 65536]);
            __half2 qq = __floats2half2_rn(vb[gi + 131072], vb[gi + 196608]);
            v.x = *reinterpret_cast<unsigned*>(&p);
            v.y = *reinterpret_cast<unsigned*>(&qq);
          }
          sl[r * SW + y + 3] = v;
        }
      }
    }
    __syncthreads();

    const int KOFF = (3 - 64 * st) * SW + 3;  // ai = r0*SW + w0 + KOFF
#pragma unroll
    for (int j = 0; j < AG; ++j) {
      const float c = c_[j], s = s_[j];
      const float bx = fmaf(u, -s, 127.5f);
      const float by = fmaf(u, c, 127.5f);
      const float cr = ax ? s : c, br = ax ? by : bx;  // strip coord |cr|>=.65
      const float cc = ax ? c : s, bc = ax ? bx : by;  // col coord

      // global t-interval (widen +-2; ceil start keeps taps in the 3-pad)
      float t1 = (-1.f - br) / cr + 191.5f;
      float t2 = (256.f - br) / cr + 191.5f;
      float flo = fmaxf(0.f, fminf(t1, t2) - 2.f);
      float fhi = fminf((float)NT, fmaxf(t1, t2) + 2.f);
      if (fabsf(cc) < 1e-6f) {
        if (bc <= -1.f || bc >= 256.f) { flo = 1.f; fhi = 0.f; }
      } else {
        float t3 = (-1.f - bc) / cc + 191.5f;
        float t4 = (256.f - bc) / cc + 191.5f;
        flo = fmaxf(flo, fminf(t3, t4) - 2.f);
        fhi = fminf(fhi, fmaxf(t3, t4) + 2.f);
      }
      const int glo = (int)ceilf(flo);
      const int ghi = (int)fhi;

      // strip partition (|cr|>=0.65, never degenerate); identical boundary
      // expressions in all strips -> exact split, no gap/double-count
      float ta = ((float)(64 * st) - br) / cr + 191.5f;
      float tb = ((float)(64 * st + 64) - br) / cr + 191.5f;
      int ia = (int)ceilf(ta);
      int ib = (int)ceilf(tb);
      int lo, hi;
      if (cr > 0.f) {
        lo = (st == 0) ? glo : max(glo, ia);
        hi = (st == 3) ? ghi : min(ghi, ib);
      } else {
        lo = (st == 3) ? glo : max(glo, ib);
        hi = (st == 0) ? ghi : min(ghi, ia);
      }
      const int start = lo + ((q - lo) & 3);
      const int d = hi - start;
      const int n = d > 0 ? (d + 3) >> 2 : 0;
      float t = (float)start - 191.5f;  // half-integers: t += 4 exact in fp32
      float a0 = acc[j].x, a1 = acc[j].y, a2 = acc[j].z, a3 = acc[j].w;
#pragma unroll 2
      for (int k = 0; k < n; ++k, t += 4.f) {
        float rr = fmaf(t, cr, br);
        float ww = fmaf(t, cc, bc);
        float r0f = floorf(rr), w0f = floorf(ww);
        float fr = rr - r0f, fw = ww - w0f;
        int ai = (int)fmaf(r0f, (float)SW, w0f) + KOFF;  // exact: |.| < 2^24
        uint2 D00 = sl[ai], D01 = sl[ai + 1];
        uint2 D10 = sl[ai + SW], D11 = sl[ai + SW + 1];
        __half2 fw2 = __float2half2_rn(fw);
        __half2 e00 = *reinterpret_cast<__half2*>(&D00.x);
        __half2 o00 = *reinterpret_cast<__half2*>(&D00.y);
        __half2 e01 = *reinterpret_cast<__half2*>(&D01.x);
        __half2 o01 = *reinterpret_cast<__half2*>(&D01.y);
        __half2 e10 = *reinterpret_cast<__half2*>(&D10.x);
        __half2 o10 = *reinterpret_cast<__half2*>(&D10.y);
        __half2 e11 = *reinterpret_cast<__half2*>(&D11.x);
        __half2 o11 = *reinterpret_cast<__half2*>(&D11.y);
        // col-lerp in packed fp16: z01 and z23 simultaneously, both rows
        __half2 hxa = __hfma2(__hsub2(e01, e00), fw2, e00);  // top, z0z1
        __half2 hxb = __hfma2(__hsub2(o01, o00), fw2, o00);  // top, z2z3
        __half2 hya = __hfma2(__hsub2(e11, e10), fw2, e10);  // bot, z0z1
        __half2 hyb = __hfma2(__hsub2(o11, o10), fw2, o10);  // bot, z2z3
        float omfr = 1.f - fr;
        a0 = fmaf(__low2float(hxa), omfr, a0);
        a0 = fmaf(__low2float(hya), fr, a0);
        a1 = fmaf(__high2float(hxa), omfr, a1);
        a1 = fmaf(__high2float(hya), fr, a1);
        a2 = fmaf(__low2float(hxb), omfr, a2);
        a2 = fmaf(__low2float(hyb), fr, a2);
        a3 = fmaf(__high2float(hxb), omfr, a3);
        a3 = fmaf(__high2float(hyb), fr, a3);
      }
      acc[j] = make_float4(a0, a1, a2, a3);
    }
  }

  // reduce 4 t-quarters (ps aliases dead slice) and write 4 z per angle
#pragma unroll
  for (int j = 0; j < AG; ++j) {
    __syncthreads();
    ps[tid] = acc[j];
    __syncthreads();
    if (tid < 256) {
      float4 A = ps[col], B = ps[256 + col], C = ps[512 + col],
             D = ps[768 + col];
      const int a = ag * AG + j;
      const int zb = zq * 4;
      out[(a * ZDIM + zb + 0) * XDIM + col] = A.x + B.x + C.x + D.x;
      out[(a * ZDIM + zb + 1) * XDIM + col] = A.y + B.y + C.y + D.y;
      out[(a * ZDIM + zb + 2) * XDIM + col] = A.z + B.z + C.z + D.z;
      out[(a * ZDIM + zb + 3) * XDIM + col] = A.w + B.w + C.w + D.w;
    }
  }
}

extern "C" void kernel_launch(void* const* d_in, const int* in_sizes, int n_in,
                              void* d_out, int out_size, void* d_ws, size_t ws_size,
                              hipStream_t stream) {
  const float* vol = (const float*)d_in[0];
  const float* phis = (const float*)d_in[1];
  float* out = (float*)d_out;
  (void)hipFuncSetAttribute((const void*)proj_kernel,
                            hipFuncAttributeMaxDynamicSharedMemorySize,
                            SMEM_BYTES);
  dim3 grid(ZDIM / 4, NA / AG);
  proj_kernel<<<grid, 1024, SMEM_BYTES, stream>>>(vol, phis, out);
}